// Round 2
// baseline (203.592 us; speedup 1.0000x reference)
//
#include <hip/hip_runtime.h>
#include <hip/hip_bf16.h>
#include <math.h>

// ChamferLoss: pred [32,4096,3] f32, gt [32,4096,3] f32 -> scalar f32.
//
// min_m d2 = p2 + min_m (g2[m] - 2*dot)  -> inner loop = 3 FMA + 1 min per pair.
//
// R1 post-mortem: 4-wave blocks sharing one LDS unit made ds_read_b128 the
// binding pipe (4 waves x 12cyc = 48 > 32 VALU cyc/point -> VALUBusy 67%).
// R2: QPT=16 -> 64 VALU ops per ds_read (LDS demand 48 << 128 issue cyc).
// Targets split 4-ways across blocks (grid stays 256 = 1 block/CU); partial
// per-query mins merged via uint atomicMin on clamped d2 (>=0 so uint order
// == float order). ws[262144] u32 init to 0xFF (uint-max) by hipMemsetAsync.

#define TPB   256
#define QPT   16          // 4096 queries per block
#define NPTS  4096
#define KT    4           // target splits
#define TCH   (NPTS / KT) // 1024 targets per block
#define NQTOT (2 * 32 * NPTS)   // 262144 query slots (both directions)

__global__ __launch_bounds__(TPB) void chamfer_main(
    const float* __restrict__ pred,
    const float* __restrict__ gt,
    unsigned int* __restrict__ wsmin)
{
    // grid.x = 256: dir (2) x batch (32) x target-quarter (4)
    const int bx  = blockIdx.x;
    const int dir = bx >> 7;
    const int rem = bx & 127;
    const int b   = rem >> 2;
    const int kt  = rem & 3;

    const float* __restrict__ qbase = (dir ? gt : pred) + (size_t)b * NPTS * 3;
    const float* __restrict__ tbase = (dir ? pred : gt) + (size_t)b * NPTS * 3;

    __shared__ float4 sT[TCH];   // (-2x, -2y, -2z, x^2+y^2+z^2)  16 KB

    const int tid = threadIdx.x;

    // Stage this block's target quarter: 4 points per thread (one-time cost)
    for (int j = tid; j < TCH; j += TPB) {
        const float* tp = tbase + (size_t)(kt * TCH + j) * 3;
        float x = tp[0], y = tp[1], z = tp[2];
        sT[j] = make_float4(-2.0f * x, -2.0f * y, -2.0f * z,
                            fmaf(x, x, fmaf(y, y, z * z)));
    }

    // Load 16 query points per thread (qid = i*256 + tid covers all 4096)
    float qx[QPT], qy[QPT], qz[QPT], mn[QPT];
#pragma unroll
    for (int i = 0; i < QPT; ++i) {
        const float* p = qbase + (size_t)(i * TPB + tid) * 3;
        qx[i] = p[0]; qy[i] = p[1]; qz[i] = p[2];
        mn[i] = 1e30f;
    }

    __syncthreads();

    // 64 VALU ops per broadcast ds_read_b128 -> VALU-bound
#pragma unroll 2
    for (int j = 0; j < TCH; ++j) {
        const float4 g = sT[j];
#pragma unroll
        for (int i = 0; i < QPT; ++i) {
            float d = fmaf(qx[i], g.x,
                      fmaf(qy[i], g.y,
                      fmaf(qz[i], g.z, g.w)));
            mn[i] = fminf(mn[i], d);
        }
    }

    // Partial result: d2 = p2 + min, clamped >= 1e-12 (so non-negative ->
    // uint bit-pattern order == float order). Merge across the 4 sibling
    // blocks with atomicMin. ws pre-initialized to 0xFFFFFFFF (uint max).
    unsigned int* wq = wsmin + (size_t)(dir * 32 + b) * NPTS;
#pragma unroll
    for (int i = 0; i < QPT; ++i) {
        float p2 = fmaf(qx[i], qx[i], fmaf(qy[i], qy[i], qz[i] * qz[i]));
        float d2 = fmaxf(mn[i] + p2, 1e-12f);
        atomicMin(&wq[i * TPB + tid], __float_as_uint(d2));
    }
}

// sqrt + mean over all 262144 query mins, accumulate into out[0]
__global__ __launch_bounds__(TPB) void chamfer_finish(
    const unsigned int* __restrict__ wsmin,
    float* __restrict__ out)
{
    __shared__ float swave[TPB / 64];
    const int tid  = threadIdx.x;
    const int base = blockIdx.x * (TPB * 4) + tid;

    float s = 0.0f;
#pragma unroll
    for (int r = 0; r < 4; ++r) {
        float d2 = __uint_as_float(wsmin[base + r * TPB]);
        s += sqrtf(d2);
    }

#pragma unroll
    for (int off = 32; off > 0; off >>= 1)
        s += __shfl_down(s, off, 64);
    const int wid = tid >> 6, lane = tid & 63;
    if (lane == 0) swave[wid] = s;
    __syncthreads();
    if (tid == 0) {
        float tot = swave[0] + swave[1] + swave[2] + swave[3];
        atomicAdd(out, tot * (1.0f / 131072.0f));
    }
}

extern "C" void kernel_launch(void* const* d_in, const int* in_sizes, int n_in,
                              void* d_out, int out_size, void* d_ws, size_t ws_size,
                              hipStream_t stream)
{
    const float* pred = (const float*)d_in[0];
    const float* gt   = (const float*)d_in[1];
    float* out        = (float*)d_out;
    unsigned int* wsmin = (unsigned int*)d_ws;

    // Identity for uint atomicMin: 0xFFFFFFFF. Also zero the scalar output.
    hipMemsetAsync(d_ws, 0xFF, (size_t)NQTOT * sizeof(unsigned int), stream);
    hipMemsetAsync(d_out, 0, sizeof(float), stream);

    chamfer_main<<<dim3(256), dim3(TPB), 0, stream>>>(pred, gt, wsmin);
    chamfer_finish<<<dim3(NQTOT / (TPB * 4)), dim3(TPB), 0, stream>>>(wsmin, out);
}

// Round 3
// 147.370 us; speedup vs baseline: 1.3815x; 1.3815x over previous
//
#include <hip/hip_runtime.h>
#include <hip/hip_bf16.h>
#include <math.h>

// ChamferLoss: pred [32,4096,3] f32, gt [32,4096,3] f32 -> scalar f32.
//
// min_m d2 = p2 + min_m (g2[m] - 2*dot)  -> inner loop = 3 FMA + 1 min / pair.
//
// R1: QPT=4 was LDS-pipe-bound (4 waves x 12cyc ds_read > 32cyc VALU -> 67%).
// R2: QPT=16 spilled (needs 64 live floats, VGPR_Count=52 -> scratch traffic;
//     VALUBusy stuck at 64%, 36% of peak useful ops).
// R3: QPT=8 (40 live floats, no spill; VALU:LDS issue = 16:12 -> VALU-bound)
//     grid 512 = dir(2) x batch(32) x qsplit(2) x tsplit(4) -> 2 blocks/CU
//     (8 waves/CU for latency hiding). atomicMin merge unchanged.

#define TPB   256
#define QPT   8            // 2048 queries per block
#define NPTS  4096
#define TCH   1024         // targets per block (16 KB LDS)
#define NQTOT (2 * 32 * NPTS)   // 262144 query slots (both directions)

__global__ __launch_bounds__(TPB) void chamfer_main(
    const float* __restrict__ pred,
    const float* __restrict__ gt,
    unsigned int* __restrict__ wsmin)
{
    // grid.x = 512: dir (2) x batch (32) x qsplit (2) x tsplit (4)
    const int bx  = blockIdx.x;
    const int dir = bx >> 8;
    const int rem = bx & 255;
    const int b   = rem >> 3;
    const int qs  = (rem >> 2) & 1;
    const int kt  = rem & 3;

    const float* __restrict__ qbase = (dir ? gt : pred) + (size_t)b * NPTS * 3;
    const float* __restrict__ tbase = (dir ? pred : gt) + (size_t)b * NPTS * 3;

    __shared__ float4 sT[TCH];   // (-2x, -2y, -2z, x^2+y^2+z^2)  16 KB

    const int tid = threadIdx.x;

    // Stage this block's 1024-target slice: 4 points per thread
    for (int j = tid; j < TCH; j += TPB) {
        const float* tp = tbase + (size_t)(kt * TCH + j) * 3;
        float x = tp[0], y = tp[1], z = tp[2];
        sT[j] = make_float4(-2.0f * x, -2.0f * y, -2.0f * z,
                            fmaf(x, x, fmaf(y, y, z * z)));
    }

    // Load 8 query points per thread from this block's 2048-query slice
    float qx[QPT], qy[QPT], qz[QPT], mn[QPT];
#pragma unroll
    for (int i = 0; i < QPT; ++i) {
        const float* p = qbase + (size_t)(qs * (QPT * TPB) + i * TPB + tid) * 3;
        qx[i] = p[0]; qy[i] = p[1]; qz[i] = p[2];
        mn[i] = 1e30f;
    }

    __syncthreads();

    // 32 VALU insts per broadcast ds_read_b128 (issue 64 cyc vs 12 cyc LDS)
#pragma unroll 4
    for (int j = 0; j < TCH; ++j) {
        const float4 g = sT[j];
#pragma unroll
        for (int i = 0; i < QPT; ++i) {
            float d = fmaf(qx[i], g.x,
                      fmaf(qy[i], g.y,
                      fmaf(qz[i], g.z, g.w)));
            mn[i] = fminf(mn[i], d);
        }
    }

    // d2 = p2 + min, clamped >= 1e-12 (non-negative -> uint order == float
    // order). Merge across the 4 sibling tsplit blocks with atomicMin.
    unsigned int* wq = wsmin + (size_t)(dir * 32 + b) * NPTS;
#pragma unroll
    for (int i = 0; i < QPT; ++i) {
        float p2 = fmaf(qx[i], qx[i], fmaf(qy[i], qy[i], qz[i] * qz[i]));
        float d2 = fmaxf(mn[i] + p2, 1e-12f);
        atomicMin(&wq[qs * (QPT * TPB) + i * TPB + tid], __float_as_uint(d2));
    }
}

// sqrt + mean over all 262144 query mins, accumulate into out[0]
__global__ __launch_bounds__(TPB) void chamfer_finish(
    const unsigned int* __restrict__ wsmin,
    float* __restrict__ out)
{
    __shared__ float swave[TPB / 64];
    const int tid  = threadIdx.x;
    const int base = blockIdx.x * (TPB * 4) + tid;

    float s = 0.0f;
#pragma unroll
    for (int r = 0; r < 4; ++r) {
        float d2 = __uint_as_float(wsmin[base + r * TPB]);
        s += sqrtf(d2);
    }

#pragma unroll
    for (int off = 32; off > 0; off >>= 1)
        s += __shfl_down(s, off, 64);
    const int wid = tid >> 6, lane = tid & 63;
    if (lane == 0) swave[wid] = s;
    __syncthreads();
    if (tid == 0) {
        float tot = swave[0] + swave[1] + swave[2] + swave[3];
        atomicAdd(out, tot * (1.0f / 131072.0f));
    }
}

extern "C" void kernel_launch(void* const* d_in, const int* in_sizes, int n_in,
                              void* d_out, int out_size, void* d_ws, size_t ws_size,
                              hipStream_t stream)
{
    const float* pred = (const float*)d_in[0];
    const float* gt   = (const float*)d_in[1];
    float* out        = (float*)d_out;
    unsigned int* wsmin = (unsigned int*)d_ws;

    // Identity for uint atomicMin: 0xFFFFFFFF. Also zero the scalar output.
    hipMemsetAsync(d_ws, 0xFF, (size_t)NQTOT * sizeof(unsigned int), stream);
    hipMemsetAsync(d_out, 0, sizeof(float), stream);

    chamfer_main<<<dim3(512), dim3(TPB), 0, stream>>>(pred, gt, wsmin);
    chamfer_finish<<<dim3(NQTOT / (TPB * 4)), dim3(TPB), 0, stream>>>(wsmin, out);
}

// Round 4
// 140.991 us; speedup vs baseline: 1.4440x; 1.0452x over previous
//
#include <hip/hip_runtime.h>
#include <hip/hip_bf16.h>
#include <math.h>

// ChamferLoss: pred [32,4096,3] f32, gt [32,4096,3] f32 -> scalar f32.
//
// min_m d2 = p2 + min_m (g2[m] - 2*dot)  -> 3 FMA + 1 min per pair (scalar).
//
// R3 post-mortem: VALUBusy 100% but 1.8x useful-inst floor; VGPR_Count=36
// proves the compiler's occupancy heuristic spilled query arrays to AGPRs
// (v_accvgpr_* are VALU). R4:
//  - __launch_bounds__(256,2): VGPR cap 256, no AGPR shuffle (~95 needed).
//  - v_pk_fma_f32 (2 fp32 FMA/inst, the 157TF path) on query pairs, with
//    VOP3P op_sel broadcasting target components straight from the
//    ds_read_b128 quad (zero splat movs).
//  - 2 targets/iter so mins fold as v_min3_f32 -> 8 insts / (2q x 2t)
//    = 2 insts per pair (vs 4 scalar).
//  - QPT=16 halves per-wave LDS traffic: LDS 20.5us < VALU 27.3us floor.
// Grid 512 = dir(2) x batch(32) x tsplit(8): 4096 queries x 512 targets per
// block, 2 blocks/CU. Cross-block merge via uint atomicMin on clamped d2.

#define TPB   256
#define QPT   16            // queries per thread; 4096 per block
#define QP    (QPT / 2)     // packed query pairs
#define NPTS  4096
#define TSPL  8
#define TCH   (NPTS / TSPL) // 512 targets per block (8 KB LDS)
#define NQTOT (2 * 32 * NPTS)

typedef float vf2 __attribute__((ext_vector_type(2)));
typedef float vf4 __attribute__((ext_vector_type(4)));

// d = q * bcast(g.lo) + bcast(g.hi)   [one v_pk_fma_f32]
__device__ __forceinline__ vf2 pk_fma_blo_bhi(vf2 q, vf2 g) {
    vf2 d;
    asm("v_pk_fma_f32 %0, %1, %2, %3 op_sel:[0,0,1] op_sel_hi:[1,0,1]"
        : "=v"(d) : "v"(q), "v"(g), "v"(g));
    return d;
}
// d = q * bcast(g.hi) + c
__device__ __forceinline__ vf2 pk_fma_bhi(vf2 q, vf2 g, vf2 c) {
    vf2 d;
    asm("v_pk_fma_f32 %0, %1, %2, %3 op_sel:[0,1,0] op_sel_hi:[1,1,1]"
        : "=v"(d) : "v"(q), "v"(g), "v"(c));
    return d;
}
// d = q * bcast(g.lo) + c
__device__ __forceinline__ vf2 pk_fma_blo(vf2 q, vf2 g, vf2 c) {
    vf2 d;
    asm("v_pk_fma_f32 %0, %1, %2, %3 op_sel:[0,0,0] op_sel_hi:[1,0,1]"
        : "=v"(d) : "v"(q), "v"(g), "v"(c));
    return d;
}

__global__ __launch_bounds__(TPB, 2) void chamfer_main(
    const float* __restrict__ pred,
    const float* __restrict__ gt,
    unsigned int* __restrict__ wsmin)
{
    // grid.x = 512: dir (2) x batch (32) x tsplit (8)
    const int bx  = blockIdx.x;
    const int dir = bx >> 8;
    const int rem = bx & 255;
    const int b   = rem >> 3;
    const int kt  = rem & 7;

    const float* __restrict__ qbase = (dir ? gt : pred) + (size_t)b * NPTS * 3;
    const float* __restrict__ tbase = (dir ? pred : gt) + (size_t)b * NPTS * 3;

    __shared__ vf4 sT[TCH];     // (-2x, -2y, -2z, x^2+y^2+z^2)  8 KB

    const int tid = threadIdx.x;

    // Stage this block's 512-target slice: 2 points per thread
    for (int j = tid; j < TCH; j += TPB) {
        const float* tp = tbase + (size_t)(kt * TCH + j) * 3;
        float x = tp[0], y = tp[1], z = tp[2];
        vf4 t; t[0] = -2.0f * x; t[1] = -2.0f * y; t[2] = -2.0f * z;
        t[3] = fmaf(x, x, fmaf(y, y, z * z));
        sT[j] = t;
    }

    // Load 16 queries per thread, packed 2-per-register-pair
    vf2 qx2[QP], qy2[QP], qz2[QP];
    float mn[QPT];
#pragma unroll
    for (int p = 0; p < QP; ++p) {
#pragma unroll
        for (int h = 0; h < 2; ++h) {
            const int i = 2 * p + h;
            const float* q = qbase + (size_t)(i * TPB + tid) * 3;
            qx2[p][h] = q[0]; qy2[p][h] = q[1]; qz2[p][h] = q[2];
            mn[i] = 1e30f;
        }
    }

    __syncthreads();

    // 2 targets x 8 query-pairs per iter: 48 pk_fma + 16 min3 = 64 VALU
    // insts per 2 ds_read_b128  -> VALU-bound, 2 insts per (q,t) pair.
#pragma unroll 2
    for (int j = 0; j < TCH; j += 2) {
        const vf4 G0 = sT[j];
        const vf4 G1 = sT[j + 1];
        const vf2 g0xy = __builtin_shufflevector(G0, G0, 0, 1);
        const vf2 g0zw = __builtin_shufflevector(G0, G0, 2, 3);
        const vf2 g1xy = __builtin_shufflevector(G1, G1, 0, 1);
        const vf2 g1zw = __builtin_shufflevector(G1, G1, 2, 3);
#pragma unroll
        for (int p = 0; p < QP; ++p) {
            vf2 d0 = pk_fma_blo_bhi(qz2[p], g0zw);   // qz*g.z + g.w
            d0 = pk_fma_bhi(qy2[p], g0xy, d0);       // + qy*g.y
            d0 = pk_fma_blo(qx2[p], g0xy, d0);       // + qx*g.x
            vf2 d1 = pk_fma_blo_bhi(qz2[p], g1zw);
            d1 = pk_fma_bhi(qy2[p], g1xy, d1);
            d1 = pk_fma_blo(qx2[p], g1xy, d1);
            mn[2 * p]     = fminf(fminf(d0[0], d1[0]), mn[2 * p]);     // v_min3
            mn[2 * p + 1] = fminf(fminf(d0[1], d1[1]), mn[2 * p + 1]); // v_min3
        }
    }

    // d2 = p2 + min, clamp >=1e-12 (positive -> uint order == float order);
    // merge across the 8 sibling tsplit blocks with atomicMin.
    unsigned int* wq = wsmin + (size_t)(dir * 32 + b) * NPTS;
#pragma unroll
    for (int p = 0; p < QP; ++p) {
        vf2 p2 = qx2[p] * qx2[p] + qy2[p] * qy2[p] + qz2[p] * qz2[p];
#pragma unroll
        for (int h = 0; h < 2; ++h) {
            const int i = 2 * p + h;
            float d2 = fmaxf(mn[i] + p2[h], 1e-12f);
            atomicMin(&wq[i * TPB + tid], __float_as_uint(d2));
        }
    }
}

// sqrt + mean over all 262144 query mins, accumulate into out[0]
__global__ __launch_bounds__(TPB) void chamfer_finish(
    const unsigned int* __restrict__ wsmin,
    float* __restrict__ out)
{
    __shared__ float swave[TPB / 64];
    const int tid  = threadIdx.x;
    const int base = blockIdx.x * (TPB * 4) + tid;

    float s = 0.0f;
#pragma unroll
    for (int r = 0; r < 4; ++r) {
        float d2 = __uint_as_float(wsmin[base + r * TPB]);
        s += sqrtf(d2);
    }

#pragma unroll
    for (int off = 32; off > 0; off >>= 1)
        s += __shfl_down(s, off, 64);
    const int wid = tid >> 6, lane = tid & 63;
    if (lane == 0) swave[wid] = s;
    __syncthreads();
    if (tid == 0) {
        float tot = swave[0] + swave[1] + swave[2] + swave[3];
        atomicAdd(out, tot * (1.0f / 131072.0f));
    }
}

extern "C" void kernel_launch(void* const* d_in, const int* in_sizes, int n_in,
                              void* d_out, int out_size, void* d_ws, size_t ws_size,
                              hipStream_t stream)
{
    const float* pred = (const float*)d_in[0];
    const float* gt   = (const float*)d_in[1];
    float* out        = (float*)d_out;
    unsigned int* wsmin = (unsigned int*)d_ws;

    // Identity for uint atomicMin: 0xFFFFFFFF. Zero the scalar output.
    hipMemsetAsync(d_ws, 0xFF, (size_t)NQTOT * sizeof(unsigned int), stream);
    hipMemsetAsync(d_out, 0, sizeof(float), stream);

    chamfer_main<<<dim3(512), dim3(TPB), 0, stream>>>(pred, gt, wsmin);
    chamfer_finish<<<dim3(NQTOT / (TPB * 4)), dim3(TPB), 0, stream>>>(wsmin, out);
}